// Round 9
// baseline (690.763 us; speedup 1.0000x reference)
//
#include <hip/hip_runtime.h>
#include <hip/hip_fp16.h>

// GCNConv (self-loops, symmetric norm) + bias + PReLU, fp32, N=100k, D=64, E=1.6M.
//
// CSR-free: bucket counting sort to 64-dst buckets, then per-bucket LDS
// scatter-accumulate (no global float atomics, no csr array):
//   1. k_detect:  edge_index storage (int64 vs int32)
//   2. k_p1hist:  per-block LDS histogram over buckets (dst>>6) -> blkcnt matrix
//   3. k_colscan: exclusive scan each bucket's row over the 256 blocks -> btot
//   4. k_bbase:   exclusive scan btot -> bucket bases (bbase[nbuk]=E)
//   5. k_p1scat:  scatter edges bucket-contiguously, pack (dst&63)<<17|src
//   6. k_p2cnt:   per-bucket LDS count of 64 dsts -> dinv
//   7. k_gemm:    xwsh = fp16((x @ W) * dinv[row])   (LDS-tiled, 128 rows/block)
//   8. k_bgather: per-bucket acc[64][64] in LDS; ds_add per edge; fused epilogue

static inline int iceil(long long a, int b) { return (int)((a + (long long)b - 1) / b); }

#define NBLK 256          // pass-1 blocks (count-matrix width)
#define BKT 64            // dsts per bucket
#define NBUK_MAX 2048     // supports N <= 131072

__global__ void k_detect(const int* __restrict__ ei, long long n_i32_min, int* flag) {
    __shared__ int nz;
    if (threadIdx.x == 0) nz = 0;
    __syncthreads();
    long long half = n_i32_min >> 1;
    long long step = half / 4096;
    if (step == 0) step = 1;
    for (int t = threadIdx.x; t < 4096; t += blockDim.x) {
        long long k = (long long)t * step;
        if (k < half && ei[2 * k + 1] != 0) nz = 1;  // benign race
    }
    __syncthreads();
    if (threadIdx.x == 0) *flag = nz ? 1 : 2;
}

// per-block histogram over nbuk buckets; blkcnt[b*NBLK + blk] = count
__global__ __launch_bounds__(256) void k_p1hist(const int* __restrict__ ei,
                                                const int* __restrict__ flag,
                                                int* __restrict__ blkcnt,
                                                long long E, int nbuk, int chunk) {
    __shared__ int hist[NBUK_MAX];
    for (int i = threadIdx.x; i < nbuk; i += 256) hist[i] = 0;
    __syncthreads();
    const int st = *flag;
    long long beg = (long long)blockIdx.x * chunk;
    long long end = beg + chunk; if (end > E) end = E;
    for (long long e = beg + threadIdx.x; e < end; e += 256) {
        int d = ei[(E + e) * st];
        atomicAdd(&hist[d >> 6], 1);
    }
    __syncthreads();
    for (int i = threadIdx.x; i < nbuk; i += 256)
        blkcnt[i * NBLK + blockIdx.x] = hist[i];
}

// per-bucket exclusive scan across the NBLK blocks; total -> btot
__global__ __launch_bounds__(NBLK) void k_colscan(int* __restrict__ blkcnt,
                                                  int* __restrict__ btot) {
    __shared__ int sh[NBLK];
    const int b = blockIdx.x, t = threadIdx.x;
    int v = blkcnt[b * NBLK + t];
    sh[t] = v;
    __syncthreads();
    for (int off = 1; off < NBLK; off <<= 1) {
        int tv = (t >= off) ? sh[t - off] : 0;
        __syncthreads();
        sh[t] += tv;
        __syncthreads();
    }
    blkcnt[b * NBLK + t] = sh[t] - v;           // exclusive
    if (t == NBLK - 1) btot[b] = sh[t];
}

// exclusive scan of bucket totals (up to 2048) -> bbase; bbase[nbuk] = E
__global__ __launch_bounds__(1024) void k_bbase(const int* __restrict__ btot,
                                                int* __restrict__ bbase, int nbuk) {
    __shared__ int ps[1024];
    const int t = threadIdx.x;
    int a0 = (2 * t < nbuk) ? btot[2 * t] : 0;
    int a1 = (2 * t + 1 < nbuk) ? btot[2 * t + 1] : 0;
    int pair = a0 + a1;
    ps[t] = pair;
    __syncthreads();
    for (int off = 1; off < 1024; off <<= 1) {
        int v = (t >= off) ? ps[t - off] : 0;
        __syncthreads();
        ps[t] += v;
        __syncthreads();
    }
    int base = ps[t] - pair;  // exclusive pair base
    if (2 * t < nbuk)      bbase[2 * t] = base;
    if (2 * t + 1 < nbuk)  bbase[2 * t + 1] = base + a0;
    if (2 * t == nbuk)     bbase[nbuk] = base;            // nbuk even
    if (2 * t + 1 == nbuk) bbase[nbuk] = base + a0;       // nbuk odd
}

// scatter edges to bucket-contiguous part[]; rank via LDS atomics only
__global__ __launch_bounds__(256) void k_p1scat(const int* __restrict__ ei,
                                                const int* __restrict__ flag,
                                                const int* __restrict__ blkcnt,
                                                const int* __restrict__ bbase,
                                                int* __restrict__ part,
                                                long long E, int nbuk, int chunk) {
    __shared__ int sbase[NBUK_MAX];
    __shared__ int lcnt[NBUK_MAX];
    for (int i = threadIdx.x; i < nbuk; i += 256) {
        sbase[i] = bbase[i] + blkcnt[i * NBLK + blockIdx.x];
        lcnt[i] = 0;
    }
    __syncthreads();
    const int st = *flag;
    long long beg = (long long)blockIdx.x * chunk;
    long long end = beg + chunk; if (end > E) end = E;
    for (long long e = beg + threadIdx.x; e < end; e += 256) {
        int s = ei[e * st];
        int d = ei[(E + e) * st];
        int b = d >> 6;
        int r = atomicAdd(&lcnt[b], 1);
        part[sbase[b] + r] = ((d & 63) << 17) | s;   // s < 2^17
    }
}

// per-bucket count of 64 dsts -> dinv
__global__ __launch_bounds__(256) void k_p2cnt(const int* __restrict__ part,
                                               const int* __restrict__ bbase,
                                               float* __restrict__ dinv, int N) {
    __shared__ int cnt[BKT];
    const int t = threadIdx.x;
    if (t < BKT) cnt[t] = 0;
    __syncthreads();
    const int beg = bbase[blockIdx.x], end = bbase[blockIdx.x + 1];
    for (int i = beg + t; i < end; i += 256)
        atomicAdd(&cnt[(part[i] >> 17) & 63], 1);
    __syncthreads();
    if (t < BKT) {
        int d = blockIdx.x * BKT + t;
        if (d < N) dinv[d] = rsqrtf((float)cnt[t] + 1.0f);  // +1 self loop
    }
}

// xwsh = fp16((x @ W) * dinv[row]).  LDS-tiled, coalesced loads, 8x4 per thread.
__global__ __launch_bounds__(256) void k_gemm(const float* __restrict__ x,
                                              const float* __restrict__ W,
                                              const float* __restrict__ dinv,
                                              __half* __restrict__ xwsh, int N) {
    __shared__ float Ws[64 * 64];
    __shared__ float xT[64][132];
    const int tid = threadIdx.x;
    {
        const float4* W4 = (const float4*)W;
        float4* Ws4 = (float4*)Ws;
#pragma unroll
        for (int j = 0; j < 4; ++j) Ws4[tid + 256 * j] = W4[tid + 256 * j];
    }
    const int tile0 = blockIdx.x * 128;
    {
        const int lr = tid >> 4;
        const int c4 = (tid & 15) * 4;
#pragma unroll
        for (int i = 0; i < 8; ++i) {
            int row = lr + 16 * i;
            int gr = tile0 + row;
            if (gr >= N) gr = N - 1;
            float4 v = *(const float4*)(x + (long long)gr * 64 + c4);
            xT[c4 + 0][row] = v.x;
            xT[c4 + 1][row] = v.y;
            xT[c4 + 2][row] = v.z;
            xT[c4 + 3][row] = v.w;
        }
    }
    __syncthreads();
    const int ri = tid >> 4;
    const int ci = tid & 15;
    float acc[8][4];
#pragma unroll
    for (int j = 0; j < 8; ++j)
#pragma unroll
        for (int c = 0; c < 4; ++c) acc[j][c] = 0.0f;
#pragma unroll 4
    for (int k = 0; k < 64; ++k) {
        float4 xa = *(const float4*)&xT[k][8 * ri];
        float4 xb = *(const float4*)&xT[k][8 * ri + 4];
        float4 wv = *(const float4*)&Ws[k * 64 + 4 * ci];
        float xr[8] = {xa.x, xa.y, xa.z, xa.w, xb.x, xb.y, xb.z, xb.w};
        float wc[4] = {wv.x, wv.y, wv.z, wv.w};
#pragma unroll
        for (int j = 0; j < 8; ++j)
#pragma unroll
            for (int c = 0; c < 4; ++c) acc[j][c] = fmaf(xr[j], wc[c], acc[j][c]);
    }
#pragma unroll
    for (int j = 0; j < 8; ++j) {
        int gr = tile0 + 8 * ri + j;
        if (gr < N) {
            float di = dinv[gr];
            __half2 h01 = __floats2half2_rn(acc[j][0] * di, acc[j][1] * di);
            __half2 h23 = __floats2half2_rn(acc[j][2] * di, acc[j][3] * di);
            uint2 u;
            u.x = *(unsigned int*)&h01;
            u.y = *(unsigned int*)&h23;
            *(uint2*)(xwsh + (long long)gr * 64 + 4 * ci) = u;  // 8B store
        }
    }
}

// per-bucket scatter-accumulate: acc[64][64] fp32 in LDS (16KB), ds_add per edge
// (addr = dl*64+lane -> 2 lanes/bank, conflict-free); fused epilogue.
__global__ __launch_bounds__(256) void k_bgather(const int* __restrict__ part,
                                                 const int* __restrict__ bbase,
                                                 const float* __restrict__ dinv,
                                                 const __half* __restrict__ xwsh,
                                                 const float* __restrict__ b,
                                                 const float* __restrict__ pa,
                                                 float* __restrict__ out, int N) {
    __shared__ float acc[BKT][64];
    const int t = threadIdx.x;
    const int lane = t & 63, wib = t >> 6;
    for (int i = t; i < BKT * 64; i += 256) ((float*)acc)[i] = 0.0f;
    __syncthreads();
    const int beg = bbase[blockIdx.x], end = bbase[blockIdx.x + 1];
    for (int base = beg + wib * 64; base < end; base += 256) {
        int m = end - base; if (m > 64) m = 64;
        int pv = (base + lane < end) ? part[base + lane] : 0;
        int j = 0;
        for (; j + 4 <= m; j += 4) {
            int v0 = __shfl(pv, j),     v1 = __shfl(pv, j + 1);
            int v2 = __shfl(pv, j + 2), v3 = __shfl(pv, j + 3);
            float x0 = __half2float(xwsh[(long long)(v0 & 0x1FFFF) * 64 + lane]);
            float x1 = __half2float(xwsh[(long long)(v1 & 0x1FFFF) * 64 + lane]);
            float x2 = __half2float(xwsh[(long long)(v2 & 0x1FFFF) * 64 + lane]);
            float x3 = __half2float(xwsh[(long long)(v3 & 0x1FFFF) * 64 + lane]);
            atomicAdd(&acc[(v0 >> 17) & 63][lane], x0);
            atomicAdd(&acc[(v1 >> 17) & 63][lane], x1);
            atomicAdd(&acc[(v2 >> 17) & 63][lane], x2);
            atomicAdd(&acc[(v3 >> 17) & 63][lane], x3);
        }
        for (; j < m; ++j) {
            int v = __shfl(pv, j);
            float xv = __half2float(xwsh[(long long)(v & 0x1FFFF) * 64 + lane]);
            atomicAdd(&acc[(v >> 17) & 63][lane], xv);
        }
    }
    __syncthreads();
    const int tile0 = blockIdx.x * BKT;
    const float slope = pa[0];
    const float bias = b[lane];
    for (int r = wib; r < BKT; r += 4) {
        int d = tile0 + r;
        if (d >= N) break;
        float di = dinv[d];
        float self = __half2float(xwsh[(long long)d * 64 + lane]);
        float v = di * (self + acc[r][lane]) + bias;
        out[(long long)d * 64 + lane] = v >= 0.0f ? v : slope * v;
    }
}

extern "C" void kernel_launch(void* const* d_in, const int* in_sizes, int n_in,
                              void* d_out, int out_size, void* d_ws, size_t ws_size,
                              hipStream_t stream) {
    const float* x  = (const float*)d_in[0];
    const int*   ei = (const int*)d_in[1];
    const float* W  = (const float*)d_in[2];
    const float* b  = (const float*)d_in[3];
    const float* pa = (const float*)d_in[4];
    float* out = (float*)d_out;

    const int N = in_sizes[0] / 64;
    const long long E = (long long)in_sizes[1] / 2;
    const int nbuk = (N + BKT - 1) / BKT;      // 1563 for N=100k (<= NBUK_MAX)
    const int chunk = iceil(E, NBLK);          // edges per pass-1 block

    char* ws = (char*)d_ws;
    size_t o = 0;
    int*    flag   = (int*)(ws + o);  o += 256;
    int*    blkcnt = (int*)(ws + o);  o += ((size_t)nbuk * NBLK * 4 + 255) & ~(size_t)255;
    int*    btot   = (int*)(ws + o);  o += ((size_t)nbuk * 4 + 255) & ~(size_t)255;
    int*    bbase  = (int*)(ws + o);  o += ((size_t)(nbuk + 1) * 4 + 255) & ~(size_t)255;
    float*  dinv   = (float*)(ws + o); o += ((size_t)N * 4 + 255) & ~(size_t)255;
    int*    part   = (int*)(ws + o);  o += ((size_t)E * 4 + 255) & ~(size_t)255;
    __half* xwsh   = (__half*)(ws + o);  // N*64*2 = 12.8 MB; total ~22 MB

    k_detect<<<1, 256, 0, stream>>>(ei, (long long)in_sizes[1], flag);
    k_p1hist<<<NBLK, 256, 0, stream>>>(ei, flag, blkcnt, E, nbuk, chunk);
    k_colscan<<<nbuk, NBLK, 0, stream>>>(blkcnt, btot);
    k_bbase<<<1, 1024, 0, stream>>>(btot, bbase, nbuk);
    k_p1scat<<<NBLK, 256, 0, stream>>>(ei, flag, blkcnt, bbase, part, E, nbuk, chunk);
    k_p2cnt<<<nbuk, 256, 0, stream>>>(part, bbase, dinv, N);
    k_gemm<<<iceil(N, 128), 256, 0, stream>>>(x, W, dinv, xwsh, N);
    k_bgather<<<nbuk, 256, 0, stream>>>(part, bbase, dinv, xwsh, b, pa, out, N);
}

// Round 10
// 130.311 us; speedup vs baseline: 5.3009x; 5.3009x over previous
//
#include <hip/hip_runtime.h>
#include <hip/hip_fp16.h>

// GCNConv (self-loops, symmetric norm) + bias + PReLU, fp32, N=100k, D=64, E=1.6M.
//
// R8 pipeline (bucket counting sort -> CSR, fp16 message table) with a
// quarter-wave gather: 4 edges in flight per load instruction, 16 lanes/row.
//   1. k_detect:  edge_index storage (int64 vs int32)
//   2. k_p1hist:  per-block LDS histogram over buckets (dst>>7) -> blkcnt matrix
//   3. k_colscan: exclusive scan each bucket's row over blocks; totals -> btot
//   4. k_bbase:   exclusive scan btot -> bucket bases (bbase[nbuk]=E)
//   5. k_p1scat:  scatter edges bucket-contiguously, pack (dst&127)<<17|src
//   6. k_p2:      per-bucket: LDS count(128 dsts) -> scan -> offs/dinv, rank-place csr
//   7. k_gemm:    xwsh = fp16((x @ W) * dinv[row])   (LDS-tiled, 128 rows/block)
//   8. k_gather:  quarter-wave: out[d] = prelu(dinv[d]*(self + sum xwsh[src]) + b)

static inline int iceil(long long a, int b) { return (int)((a + (long long)b - 1) / b); }

#define NBLK 128          // pass-1 blocks (count-matrix width)
#define NBUK_MAX 1024     // supports N <= 131072

__global__ void k_detect(const int* __restrict__ ei, long long n_i32_min, int* flag) {
    __shared__ int nz;
    if (threadIdx.x == 0) nz = 0;
    __syncthreads();
    long long half = n_i32_min >> 1;
    long long step = half / 4096;
    if (step == 0) step = 1;
    for (int t = threadIdx.x; t < 4096; t += blockDim.x) {
        long long k = (long long)t * step;
        if (k < half && ei[2 * k + 1] != 0) nz = 1;  // benign race
    }
    __syncthreads();
    if (threadIdx.x == 0) *flag = nz ? 1 : 2;
}

// per-block histogram over nbuk buckets; blkcnt[b*NBLK + blk] = count
__global__ __launch_bounds__(256) void k_p1hist(const int* __restrict__ ei,
                                                const int* __restrict__ flag,
                                                int* __restrict__ blkcnt,
                                                long long E, int nbuk, int chunk) {
    __shared__ int hist[NBUK_MAX];
    for (int i = threadIdx.x; i < nbuk; i += 256) hist[i] = 0;
    __syncthreads();
    const int st = *flag;
    long long beg = (long long)blockIdx.x * chunk;
    long long end = beg + chunk; if (end > E) end = E;
    for (long long e = beg + threadIdx.x; e < end; e += 256) {
        int d = ei[(E + e) * st];
        atomicAdd(&hist[d >> 7], 1);
    }
    __syncthreads();
    for (int i = threadIdx.x; i < nbuk; i += 256)
        blkcnt[i * NBLK + blockIdx.x] = hist[i];
}

// per-bucket exclusive scan across the NBLK blocks; total -> btot
__global__ __launch_bounds__(NBLK) void k_colscan(int* __restrict__ blkcnt,
                                                  int* __restrict__ btot) {
    __shared__ int sh[NBLK];
    const int b = blockIdx.x, t = threadIdx.x;
    int v = blkcnt[b * NBLK + t];
    sh[t] = v;
    __syncthreads();
    for (int off = 1; off < NBLK; off <<= 1) {
        int tv = (t >= off) ? sh[t - off] : 0;
        __syncthreads();
        sh[t] += tv;
        __syncthreads();
    }
    blkcnt[b * NBLK + t] = sh[t] - v;           // exclusive
    if (t == NBLK - 1) btot[b] = sh[t];
}

// exclusive scan of bucket totals -> bbase; bbase[nbuk] = E
__global__ __launch_bounds__(1024) void k_bbase(const int* __restrict__ btot,
                                                int* __restrict__ bbase, int nbuk) {
    __shared__ int sh[1024];
    const int t = threadIdx.x;
    int v = (t < nbuk) ? btot[t] : 0;
    sh[t] = v;
    __syncthreads();
    for (int off = 1; off < 1024; off <<= 1) {
        int tv = (t >= off) ? sh[t - off] : 0;
        __syncthreads();
        sh[t] += tv;
        __syncthreads();
    }
    if (t < nbuk) bbase[t] = sh[t] - v;
    if (t == 1023) bbase[nbuk] = sh[1023];       // == E
}

// scatter edges to bucket-contiguous part[]; rank via LDS atomics only
__global__ __launch_bounds__(256) void k_p1scat(const int* __restrict__ ei,
                                                const int* __restrict__ flag,
                                                const int* __restrict__ blkcnt,
                                                const int* __restrict__ bbase,
                                                int* __restrict__ part,
                                                long long E, int nbuk, int chunk) {
    __shared__ int sbase[NBUK_MAX];
    __shared__ int lcnt[NBUK_MAX];
    for (int i = threadIdx.x; i < nbuk; i += 256) {
        sbase[i] = bbase[i] + blkcnt[i * NBLK + blockIdx.x];
        lcnt[i] = 0;
    }
    __syncthreads();
    const int st = *flag;
    long long beg = (long long)blockIdx.x * chunk;
    long long end = beg + chunk; if (end > E) end = E;
    for (long long e = beg + threadIdx.x; e < end; e += 256) {
        int s = ei[e * st];
        int d = ei[(E + e) * st];
        int b = d >> 7;
        int r = atomicAdd(&lcnt[b], 1);
        part[sbase[b] + r] = ((d & 127) << 17) | s;   // s < 2^17
    }
}

// per-bucket: count 128 dsts, scan, emit offs/dinv, rank-place csr
__global__ __launch_bounds__(256) void k_p2(const int* __restrict__ part,
                                            const int* __restrict__ bbase,
                                            int* __restrict__ offs,
                                            float* __restrict__ dinv,
                                            int* __restrict__ csr, int N) {
    __shared__ int cnt[128], inc[128], exc[128], rnk[128];
    const int b = blockIdx.x, t = threadIdx.x;
    const int beg = bbase[b], end = bbase[b + 1];
    if (t < 128) cnt[t] = 0;
    __syncthreads();
    for (int i = beg + t; i < end; i += 256)
        atomicAdd(&cnt[(part[i] >> 17) & 127], 1);
    __syncthreads();
    if (t < 128) inc[t] = cnt[t];
    __syncthreads();
    for (int off = 1; off < 128; off <<= 1) {
        int v = (t < 128 && t >= off) ? inc[t - off] : 0;
        __syncthreads();
        if (t < 128) inc[t] += v;
        __syncthreads();
    }
    if (t < 128) {
        exc[t] = inc[t] - cnt[t];
        rnk[t] = 0;
        int dst = b * 128 + t;
        if (dst < N) {
            offs[dst] = beg + exc[t];
            dinv[dst] = rsqrtf((float)cnt[t] + 1.0f);  // +1 self loop
        }
    }
    __syncthreads();
    for (int i = beg + t; i < end; i += 256) {
        int v = part[i];
        int dl = (v >> 17) & 127;
        int s = v & 0x1FFFF;
        int r = atomicAdd(&rnk[dl], 1);
        csr[beg + exc[dl] + r] = s;
    }
    if (t == 0 && b == gridDim.x - 1) offs[N] = end;   // == E
}

// xwsh = fp16((x @ W) * dinv[row]).  LDS-tiled, coalesced loads, 8x4 per thread.
__global__ __launch_bounds__(256) void k_gemm(const float* __restrict__ x,
                                              const float* __restrict__ W,
                                              const float* __restrict__ dinv,
                                              __half* __restrict__ xwsh, int N) {
    __shared__ float Ws[64 * 64];
    __shared__ float xT[64][132];
    const int tid = threadIdx.x;
    {
        const float4* W4 = (const float4*)W;
        float4* Ws4 = (float4*)Ws;
#pragma unroll
        for (int j = 0; j < 4; ++j) Ws4[tid + 256 * j] = W4[tid + 256 * j];
    }
    const int tile0 = blockIdx.x * 128;
    {
        const int lr = tid >> 4;
        const int c4 = (tid & 15) * 4;
#pragma unroll
        for (int i = 0; i < 8; ++i) {
            int row = lr + 16 * i;
            int gr = tile0 + row;
            if (gr >= N) gr = N - 1;
            float4 v = *(const float4*)(x + (long long)gr * 64 + c4);
            xT[c4 + 0][row] = v.x;
            xT[c4 + 1][row] = v.y;
            xT[c4 + 2][row] = v.z;
            xT[c4 + 3][row] = v.w;
        }
    }
    __syncthreads();
    const int ri = tid >> 4;
    const int ci = tid & 15;
    float acc[8][4];
#pragma unroll
    for (int j = 0; j < 8; ++j)
#pragma unroll
        for (int c = 0; c < 4; ++c) acc[j][c] = 0.0f;
#pragma unroll 4
    for (int k = 0; k < 64; ++k) {
        float4 xa = *(const float4*)&xT[k][8 * ri];
        float4 xb = *(const float4*)&xT[k][8 * ri + 4];
        float4 wv = *(const float4*)&Ws[k * 64 + 4 * ci];
        float xr[8] = {xa.x, xa.y, xa.z, xa.w, xb.x, xb.y, xb.z, xb.w};
        float wc[4] = {wv.x, wv.y, wv.z, wv.w};
#pragma unroll
        for (int j = 0; j < 8; ++j)
#pragma unroll
            for (int c = 0; c < 4; ++c) acc[j][c] = fmaf(xr[j], wc[c], acc[j][c]);
    }
#pragma unroll
    for (int j = 0; j < 8; ++j) {
        int gr = tile0 + 8 * ri + j;
        if (gr < N) {
            float di = dinv[gr];
            __half2 h01 = __floats2half2_rn(acc[j][0] * di, acc[j][1] * di);
            __half2 h23 = __floats2half2_rn(acc[j][2] * di, acc[j][3] * di);
            uint2 u;
            u.x = *(unsigned int*)&h01;
            u.y = *(unsigned int*)&h23;
            *(uint2*)(xwsh + (long long)gr * 64 + 4 * ci) = u;  // 8B store
        }
    }
}

// quarter-wave gather: one dst per wave, 4 edges in flight per load instr.
// group g = lane>>4 picks edge jb+g; 16 lanes load the 128B fp16 row (uint2);
// per-lane float4 accumulate; butterfly-reduce groups; lanes 0-15 store float4.
__global__ __launch_bounds__(256) void k_gather(const int* __restrict__ csr,
                                                const int* __restrict__ offs,
                                                const float* __restrict__ dinv,
                                                const __half* __restrict__ xwsh,
                                                const float* __restrict__ b,
                                                const float* __restrict__ pa,
                                                float* __restrict__ out, int N) {
    const int lane = threadIdx.x & 63;
    const int g = lane >> 4;        // edge sub-slot 0..3
    const int fl = lane & 15;       // feature quad 0..15
    const int wib = threadIdx.x >> 6;
    int gw = blockIdx.x * (blockDim.x >> 6) + wib;
    int nw = gridDim.x * (blockDim.x >> 6);
    const float slope = pa[0];
    const float4 b4 = ((const float4*)b)[fl];
    for (int d = gw; d < N; d += nw) {
        int beg = offs[d];
        int end = offs[d + 1];
        float ax = 0.f, ay = 0.f, az = 0.f, aw = 0.f;
        for (int base = beg; base < end; base += 64) {
            int m = end - base; if (m > 64) m = 64;
            int sv = (base + lane < end) ? csr[base + lane] : 0;
#pragma unroll 4
            for (int jb = 0; jb < m; jb += 4) {
                int j = jb + g;
                int s = __shfl(sv, j);
                if (j < m) {
                    uint2 u = *(const uint2*)(xwsh + (long long)s * 64 + 4 * fl);
                    float2 f01 = __half22float2(*(const __half2*)&u.x);
                    float2 f23 = __half22float2(*(const __half2*)&u.y);
                    ax += f01.x; ay += f01.y; az += f23.x; aw += f23.y;
                }
            }
        }
        // merge the 4 edge-groups (butterfly over lane bits 5,4)
        ax += __shfl_xor(ax, 32); ay += __shfl_xor(ay, 32);
        az += __shfl_xor(az, 32); aw += __shfl_xor(aw, 32);
        ax += __shfl_xor(ax, 16); ay += __shfl_xor(ay, 16);
        az += __shfl_xor(az, 16); aw += __shfl_xor(aw, 16);
        if (lane < 16) {
            uint2 u = *(const uint2*)(xwsh + (long long)d * 64 + 4 * fl);  // self
            float2 s01 = __half22float2(*(const __half2*)&u.x);
            float2 s23 = __half22float2(*(const __half2*)&u.y);
            float di = dinv[d];
            float4 v;
            v.x = di * (ax + s01.x) + b4.x;
            v.y = di * (ay + s01.y) + b4.y;
            v.z = di * (az + s23.x) + b4.z;
            v.w = di * (aw + s23.y) + b4.w;
            v.x = v.x >= 0.f ? v.x : slope * v.x;
            v.y = v.y >= 0.f ? v.y : slope * v.y;
            v.z = v.z >= 0.f ? v.z : slope * v.z;
            v.w = v.w >= 0.f ? v.w : slope * v.w;
            *(float4*)(out + (long long)d * 64 + 4 * fl) = v;
        }
    }
}

extern "C" void kernel_launch(void* const* d_in, const int* in_sizes, int n_in,
                              void* d_out, int out_size, void* d_ws, size_t ws_size,
                              hipStream_t stream) {
    const float* x  = (const float*)d_in[0];
    const int*   ei = (const int*)d_in[1];
    const float* W  = (const float*)d_in[2];
    const float* b  = (const float*)d_in[3];
    const float* pa = (const float*)d_in[4];
    float* out = (float*)d_out;

    const int N = in_sizes[0] / 64;
    const long long E = (long long)in_sizes[1] / 2;
    const int nbuk = (N + 127) >> 7;           // 782 for N=100k (<= NBUK_MAX)
    const int chunk = iceil(E, NBLK);          // edges per pass-1 block

    char* ws = (char*)d_ws;
    size_t o = 0;
    int*    flag   = (int*)(ws + o);  o += 256;
    int*    blkcnt = (int*)(ws + o);  o += ((size_t)nbuk * NBLK * 4 + 255) & ~(size_t)255;
    int*    btot   = (int*)(ws + o);  o += ((size_t)nbuk * 4 + 255) & ~(size_t)255;
    int*    bbase  = (int*)(ws + o);  o += ((size_t)(nbuk + 1) * 4 + 255) & ~(size_t)255;
    int*    offs   = (int*)(ws + o);  o += ((size_t)(N + 1) * 4 + 255) & ~(size_t)255;
    float*  dinv   = (float*)(ws + o); o += ((size_t)N * 4 + 255) & ~(size_t)255;
    int*    part   = (int*)(ws + o);  o += ((size_t)E * 4 + 255) & ~(size_t)255;
    int*    csr    = (int*)(ws + o);  o += ((size_t)E * 4 + 255) & ~(size_t)255;
    __half* xwsh   = (__half*)(ws + o);  // N*64*2 = 12.8 MB; total ~27 MB

    k_detect<<<1, 256, 0, stream>>>(ei, (long long)in_sizes[1], flag);
    k_p1hist<<<NBLK, 256, 0, stream>>>(ei, flag, blkcnt, E, nbuk, chunk);
    k_colscan<<<nbuk, NBLK, 0, stream>>>(blkcnt, btot);
    k_bbase<<<1, 1024, 0, stream>>>(btot, bbase, nbuk);
    k_p1scat<<<NBLK, 256, 0, stream>>>(ei, flag, blkcnt, bbase, part, E, nbuk, chunk);
    k_p2<<<nbuk, 256, 0, stream>>>(part, bbase, offs, dinv, csr, N);
    k_gemm<<<iceil(N, 128), 256, 0, stream>>>(x, W, dinv, xwsh, N);
    k_gather<<<2048, 256, 0, stream>>>(csr, offs, dinv, xwsh, b, pa, out, N);
}